// Round 12
// baseline (7997.767 us; speedup 1.0000x reference)
//
#include <hip/hip_runtime.h>
#include <stdint.h>

#define T_TOK 8192
#define DIM   2048
#define NEXP  16
#define NLAY  4
#define TOPK  8

#define BM 128
#define BN 256
#define BK 32
#define NT 64   // physical K-tiles; 3 emulation terms fused inside each tile

typedef _Float16 f16;
typedef f16   f16x8  __attribute__((ext_vector_type(8)));
typedef f16   f16x4  __attribute__((ext_vector_type(4)));
typedef float f32x4  __attribute__((ext_vector_type(4)));
typedef float f32x16 __attribute__((ext_vector_type(16)));
typedef float fv4    __attribute__((ext_vector_type(4)));

// ---------------- routing: fp32 logits, softmax, exact top-8 ----------------
__global__ __launch_bounds__(256) void route_kernel(
    const float* __restrict__ h, const float* __restrict__ gw,
    int* __restrict__ cnt, int* __restrict__ tok, float* __restrict__ wt)
{
  int gid  = blockIdx.x * 256 + threadIdx.x;
  int t    = gid >> 6;
  int lane = threadIdx.x & 63;
  if (t >= T_TOK) return;
  const float* hr = h + (size_t)t * DIM;
  float hreg[32];
#pragma unroll
  for (int j = 0; j < 32; ++j) hreg[j] = hr[lane + 64 * j];
  float p[16];
#pragma unroll
  for (int e = 0; e < 16; ++e) {
    const float* gr = gw + e * DIM;
    float s = 0.f;
#pragma unroll
    for (int j = 0; j < 32; ++j) s += hreg[j] * gr[lane + 64 * j];
#pragma unroll
    for (int off = 32; off; off >>= 1) s += __shfl_xor(s, off);
    p[e] = s;
  }
  float mx = p[0];
#pragma unroll
  for (int e = 1; e < 16; ++e) mx = fmaxf(mx, p[e]);
  float sum = 0.f;
#pragma unroll
  for (int e = 0; e < 16; ++e) { p[e] = expf(p[e] - mx); sum += p[e]; }
  float inv = 1.f / sum;
#pragma unroll
  for (int e = 0; e < 16; ++e) p[e] *= inv;
  if (lane < 16) {
    float mine = p[lane];
    int rank = 0;
#pragma unroll
    for (int j = 0; j < 16; ++j)
      rank += (p[j] > mine) || (p[j] == mine && j < lane);  // jax top_k tie-break
    if (rank < TOPK) {
      int pos = atomicAdd(&cnt[lane], 1);
      tok[lane * T_TOK + pos] = t;
      wt [lane * T_TOK + pos] = mine;
    }
  }
}

// ------- A: fp32 -> scaled fp16 hi/lo split (x*64 = hi + lo), row-major -----
__global__ __launch_bounds__(256) void split_kernel(
    const float* __restrict__ src, f16* __restrict__ hi, f16* __restrict__ lo, int n4)
{
  int i0 = blockIdx.x * 256 + threadIdx.x;
  int stride = gridDim.x * 256;
  for (int i = i0; i < n4; i += stride) {
    fv4 v = ((const fv4*)src)[i];
    f16x4 h4, l4;
#pragma unroll
    for (int j = 0; j < 4; ++j) {
      float x = v[j] * 64.f;       // pre-scale keeps lo parts out of fp16 denormal range
      f16 hh = (f16)x;
      h4[j] = hh;
      l4[j] = (f16)(x - (float)hh);
    }
    ((f16x4*)hi)[i] = h4;
    ((f16x4*)lo)[i] = l4;
  }
}

// ------- W: split + transpose to K-major-16B layout [E][K/8][2048][8] -------
__global__ __launch_bounds__(256) void wsplit_kernel(
    const float* __restrict__ src, f16* __restrict__ hi, f16* __restrict__ lo)
{
  const int eidx = blockIdx.z;
  const int r0   = blockIdx.y * 32;
  const int k0   = blockIdx.x * 64;
  __shared__ f16 th[32 * 9 * 8];   // [32 rows][9 chunk-slots (pad)][8 f16]
  __shared__ f16 tl[32 * 9 * 8];
  const int rr = threadIdx.x >> 3, c8 = threadIdx.x & 7;
  const float* s = src + ((size_t)eidx * DIM + r0 + rr) * DIM + k0 + c8 * 8;
  fv4 v0 = *(const fv4*)s;
  fv4 v1 = *(const fv4*)(s + 4);
  f16x8 hv, lv;
#pragma unroll
  for (int j = 0; j < 4; ++j) {
    float x = v0[j] * 64.f; f16 hh = (f16)x; hv[j] = hh; lv[j] = (f16)(x - (float)hh);
    float y = v1[j] * 64.f; f16 h2 = (f16)y; hv[4 + j] = h2; lv[4 + j] = (f16)(y - (float)h2);
  }
  *(f16x8*)&th[(rr * 9 + c8) * 8] = hv;
  *(f16x8*)&tl[(rr * 9 + c8) * 8] = lv;
  __syncthreads();
  const int c8w = threadIdx.x >> 5, rw = threadIdx.x & 31;
  f16x8 oh = *(const f16x8*)&th[(rw * 9 + c8w) * 8];
  f16x8 ol = *(const f16x8*)&tl[(rw * 9 + c8w) * 8];
  size_t o = (((size_t)eidx * (DIM / 8) + (k0 / 8 + c8w)) * DIM + r0 + rw) * 8;
  *(f16x8*)&hi[o] = oh;
  *(f16x8*)&lo[o] = ol;
}

// --- gathered grouped GEMM, 128x256, wave 64x128, 32x32x16 MFMA, K-major ----
// Both A and W staged K-major [kchunk][row][8]: all ds_read_b128 are 32
// consecutive rows x 16B = sequential, conflict-free, no swizzle anywhere.
// MFMA 32x32x16 (4061 FLOP/cyc vs 3378 for 16x16x32, half the instructions).
// LDS: A1,A2 single-buffered (16 KB) + W1,W2 double-buffered (64 KB) = 80 KB
// => 2 blocks/CU. Per kt/wave: 24 ds_read -> 48 MFMA (A1W1, A2W1, A1W2).
// Grid: XCD = n-group -> each XCD reads each expert's A slice exactly once.
__global__ __launch_bounds__(256, 2) void moe_gemm(
    const f16* __restrict__ A1, const f16* __restrict__ A2,
    const f16* __restrict__ W1t, const f16* __restrict__ W2t,
    const int* __restrict__ tok, const float* __restrict__ wt,
    const int* __restrict__ cnt, float* __restrict__ out)
{
  // b = 512p + 8q + r -> group w = 8p + r (w = e*8 + nt, XCD = nt), my = q
  const int b  = blockIdx.x;
  const int w  = (b >> 9) * 8 + (b & 7);   // 0..127
  const int my = (b >> 3) & 63;            // 0..63
  const int e  = w >> 3;
  const int ce = cnt[e];
  const int m0 = my * BM;
  if (m0 >= ce) return;
  const int n0 = (w & 7) * BN;

  __shared__ f16 lsA1[BM * BK];        // [4 kc][128 row][8], 8 KB, single-buf
  __shared__ f16 lsA2[BM * BK];
  __shared__ f16 lsW1[2][BN * BK];     // [4 kc][256 row][8], 2 x 16 KB dbuf
  __shared__ f16 lsW2[2][BN * BK];

  const int tid = threadIdx.x;   // 0..255

  // A staging K-major: slot s in {tid, tid+256}: kc = s>>7, row = s&127;
  // dest = s*16B (linear). Source = tok[row]*DIM + kt*32 + kc*8.
  const int arow = tid & 127;
  const int akc  = tid >> 7;           // slot0 kc; slot1 kc = akc+2
  const size_t atok = (size_t)tok[e * T_TOK + min(m0 + arow, ce - 1)] * DIM;
  // W staging K-major: slot s = tid + 256j: kc = j, row = tid.
  const size_t wbase = (size_t)e * (DIM / 8) * DIM * 8 + ((size_t)n0 + tid) * 8;

  auto stageA = [&](int kt) {
    const int k0 = kt * BK;
    __builtin_amdgcn_global_load_lds(
        (const __attribute__((address_space(1))) void*)(A1 + atok + k0 + akc * 8),
        (__attribute__((address_space(3))) void*)(&lsA1[tid * 8]), 16, 0, 0);
    __builtin_amdgcn_global_load_lds(
        (const __attribute__((address_space(1))) void*)(A1 + atok + k0 + (akc + 2) * 8),
        (__attribute__((address_space(3))) void*)(&lsA1[(tid + 256) * 8]), 16, 0, 0);
    __builtin_amdgcn_global_load_lds(
        (const __attribute__((address_space(1))) void*)(A2 + atok + k0 + akc * 8),
        (__attribute__((address_space(3))) void*)(&lsA2[tid * 8]), 16, 0, 0);
    __builtin_amdgcn_global_load_lds(
        (const __attribute__((address_space(1))) void*)(A2 + atok + k0 + (akc + 2) * 8),
        (__attribute__((address_space(3))) void*)(&lsA2[(tid + 256) * 8]), 16, 0, 0);
  };
  auto stageW = [&](int kt, int bb) {
    const int kc0 = kt * 4;
#pragma unroll
    for (int j = 0; j < 4; ++j) {
      __builtin_amdgcn_global_load_lds(
          (const __attribute__((address_space(1))) void*)(W1t + wbase + (size_t)(kc0 + j) * DIM * 8),
          (__attribute__((address_space(3))) void*)(&lsW1[bb][(tid + 256 * j) * 8]), 16, 0, 0);
      __builtin_amdgcn_global_load_lds(
          (const __attribute__((address_space(1))) void*)(W2t + wbase + (size_t)(kc0 + j) * DIM * 8),
          (__attribute__((address_space(3))) void*)(&lsW2[bb][(tid + 256 * j) * 8]), 16, 0, 0);
    }
  };

  const int lane = tid & 63;
  const int wid  = tid >> 6;
  const int wm   = wid & 1;           // M half (64 rows)
  const int wn   = wid >> 1;          // N half (128 cols)
  const int l31  = lane & 31;
  const int lh   = lane >> 5;         // k-half within frag

  f32x16 acc[2][4];
#pragma unroll
  for (int i = 0; i < 2; ++i)
#pragma unroll
    for (int j = 0; j < 4; ++j)
      acc[i][j] = (f32x16){0.f,0.f,0.f,0.f,0.f,0.f,0.f,0.f,0.f,0.f,0.f,0.f,0.f,0.f,0.f,0.f};

  stageA(0);
  stageW(0, 0);
  asm volatile("s_waitcnt vmcnt(0)" ::: "memory");
  __builtin_amdgcn_s_barrier();
  __builtin_amdgcn_sched_barrier(0);

  int cur = 0;
  for (int kt = 0; kt < NT; ++kt) {
    const bool pf = (kt + 1 < NT);
    f16x8 a1F[2][2], a2F[2][2], w1F[4][2], w2F[4][2];

    // ---- read A frags + W1 frags (conflict-free sequential rows)
#pragma unroll
    for (int mi = 0; mi < 2; ++mi)
#pragma unroll
      for (int ks = 0; ks < 2; ++ks) {
        int off = ((ks * 2 + lh) * 128 + wm * 64 + mi * 32 + l31) * 8;
        a1F[mi][ks] = *(const f16x8*)&lsA1[off];
        a2F[mi][ks] = *(const f16x8*)&lsA2[off];
      }
#pragma unroll
    for (int ni = 0; ni < 4; ++ni)
#pragma unroll
      for (int ks = 0; ks < 2; ++ks) {
        int off = ((ks * 2 + lh) * 256 + wn * 128 + ni * 32 + l31) * 8;
        w1F[ni][ks] = *(const f16x8*)&lsW1[cur][off];
      }
    asm volatile("s_waitcnt lgkmcnt(0)" ::: "memory");   // a/w1 frags in regs
    __builtin_amdgcn_sched_barrier(0);
    __builtin_amdgcn_s_barrier();                        // all waves done with lsA
    __builtin_amdgcn_sched_barrier(0);
    if (pf) { stageA(kt + 1); stageW(kt + 1, cur ^ 1); }

    // w2F reads ride under clusters 0-1 (dbuf'd W; compiler inserts waits)
#pragma unroll
    for (int ni = 0; ni < 4; ++ni)
#pragma unroll
      for (int ks = 0; ks < 2; ++ks) {
        int off = ((ks * 2 + lh) * 256 + wn * 128 + ni * 32 + l31) * 8;
        w2F[ni][ks] = *(const f16x8*)&lsW2[cur][off];
      }

    __builtin_amdgcn_s_setprio(1);
#pragma unroll
    for (int ks = 0; ks < 2; ++ks)
#pragma unroll
      for (int mi = 0; mi < 2; ++mi)
#pragma unroll
        for (int ni = 0; ni < 4; ++ni)
          acc[mi][ni] = __builtin_amdgcn_mfma_f32_32x32x16_f16(a1F[mi][ks], w1F[ni][ks], acc[mi][ni], 0, 0, 0);
#pragma unroll
    for (int ks = 0; ks < 2; ++ks)
#pragma unroll
      for (int mi = 0; mi < 2; ++mi)
#pragma unroll
        for (int ni = 0; ni < 4; ++ni)
          acc[mi][ni] = __builtin_amdgcn_mfma_f32_32x32x16_f16(a2F[mi][ks], w1F[ni][ks], acc[mi][ni], 0, 0, 0);
#pragma unroll
    for (int ks = 0; ks < 2; ++ks)
#pragma unroll
      for (int mi = 0; mi < 2; ++mi)
#pragma unroll
        for (int ni = 0; ni < 4; ++ni)
          acc[mi][ni] = __builtin_amdgcn_mfma_f32_32x32x16_f16(a1F[mi][ks], w2F[ni][ks], acc[mi][ni], 0, 0, 0);
    __builtin_amdgcn_s_setprio(0);

    if (pf) {
      asm volatile("s_waitcnt vmcnt(0)" ::: "memory");   // kt+1 landed
      __builtin_amdgcn_s_barrier();
      __builtin_amdgcn_sched_barrier(0);
    }
    cur ^= 1;
  }

  // epilogue: out[tok, n] += w * acc / 4096  (descale 64*64)
  // C/D 32x32: col = lane&31, row = (reg&3) + 8*(reg>>2) + 4*(lane>>5)
  const int ebase = e * T_TOK;
#pragma unroll
  for (int mi = 0; mi < 2; ++mi) {
#pragma unroll
    for (int q = 0; q < 16; ++q) {
      int pos = m0 + wm * 64 + mi * 32 + (q & 3) + 8 * (q >> 2) + 4 * lh;
      if (pos < ce) {
        int tt = tok[ebase + pos];
        float sc = wt[ebase + pos] * (1.0f / 4096.0f);
        float* orow = out + (size_t)tt * DIM + n0 + wn * 128;
#pragma unroll
        for (int ni = 0; ni < 4; ++ni)
          atomicAdd(&orow[ni * 32 + l31], sc * acc[mi][ni][q]);
      }
    }
  }
}

// ------------------------------- launcher -----------------------------------
extern "C" void kernel_launch(void* const* d_in, const int* in_sizes, int n_in,
                              void* d_out, int out_size, void* d_ws, size_t ws_size,
                              hipStream_t stream) {
  const float* x  = (const float*)d_in[0];
  const float* gw = (const float*)d_in[1];
  const float* ew = (const float*)d_in[2];
  float* out = (float*)d_out;

  char* ws = (char*)d_ws;
  float* hA  = (float*)ws;                        // 64 MB fp32 h ping buffer
  f16*   A1  = (f16*)(ws + 67108864ull);          // 32 MB
  f16*   A2  = (f16*)(ws + 100663296ull);         // 32 MB
  f16*   W1t = (f16*)(ws + 134217728ull);         // 128 MB (K-major, this layer)
  f16*   W2t = (f16*)(ws + 268435456ull);         // 128 MB
  int*   tok = (int*)(ws + 402653184ull);         // 512 KB
  float* wt  = (float*)(ws + 403177472ull);       // 512 KB
  int*   cnt = (int*)(ws + 403701760ull);         // 64 B

  const float* hin = x;
  float* houts[4] = {hA, out, hA, out};           // ping-pong; final layer -> d_out
  for (int l = 0; l < NLAY; ++l) {
    float* hout = houts[l];
    hipMemsetAsync(cnt, 0, 64, stream);
    route_kernel<<<T_TOK / 4, 256, 0, stream>>>(hin, gw + (size_t)l * NEXP * DIM, cnt, tok, wt);
    split_kernel<<<4096, 256, 0, stream>>>(hin, A1, A2, T_TOK * DIM / 4);
    {
      dim3 gt(DIM / 64, DIM / 32, NEXP);
      wsplit_kernel<<<gt, 256, 0, stream>>>(ew + (size_t)l * NEXP * DIM * DIM, W1t, W2t);
    }
    hipMemsetAsync(hout, 0, (size_t)T_TOK * DIM * 4, stream);
    moe_gemm<<<16 * 64 * 8, 256, 0, stream>>>(A1, A2, W1t, W2t, tok, wt, cnt, hout);
    hin = hout;
  }
}

// Round 13
// 7667.612 us; speedup vs baseline: 1.0431x; 1.0431x over previous
//
#include <hip/hip_runtime.h>
#include <stdint.h>

#define T_TOK 8192
#define DIM   2048
#define NEXP  16
#define NLAY  4
#define TOPK  8

#define BM 128
#define BN 256
#define BK 32
#define NT 64   // physical K-tiles; 3 emulation terms fused inside each tile

typedef _Float16 f16;
typedef f16   f16x8 __attribute__((ext_vector_type(8)));
typedef f16   f16x4 __attribute__((ext_vector_type(4)));
typedef float f32x4 __attribute__((ext_vector_type(4)));
typedef float fv4   __attribute__((ext_vector_type(4)));

// ---------------- routing: fp32 logits, softmax, exact top-8 ----------------
__global__ __launch_bounds__(256) void route_kernel(
    const float* __restrict__ h, const float* __restrict__ gw,
    int* __restrict__ cnt, int* __restrict__ tok, float* __restrict__ wt)
{
  int gid  = blockIdx.x * 256 + threadIdx.x;
  int t    = gid >> 6;
  int lane = threadIdx.x & 63;
  if (t >= T_TOK) return;
  const float* hr = h + (size_t)t * DIM;
  float hreg[32];
#pragma unroll
  for (int j = 0; j < 32; ++j) hreg[j] = hr[lane + 64 * j];
  float p[16];
#pragma unroll
  for (int e = 0; e < 16; ++e) {
    const float* gr = gw + e * DIM;
    float s = 0.f;
#pragma unroll
    for (int j = 0; j < 32; ++j) s += hreg[j] * gr[lane + 64 * j];
#pragma unroll
    for (int off = 32; off; off >>= 1) s += __shfl_xor(s, off);
    p[e] = s;
  }
  float mx = p[0];
#pragma unroll
  for (int e = 1; e < 16; ++e) mx = fmaxf(mx, p[e]);
  float sum = 0.f;
#pragma unroll
  for (int e = 0; e < 16; ++e) { p[e] = expf(p[e] - mx); sum += p[e]; }
  float inv = 1.f / sum;
#pragma unroll
  for (int e = 0; e < 16; ++e) p[e] *= inv;
  if (lane < 16) {
    float mine = p[lane];
    int rank = 0;
#pragma unroll
    for (int j = 0; j < 16; ++j)
      rank += (p[j] > mine) || (p[j] == mine && j < lane);  // jax top_k tie-break
    if (rank < TOPK) {
      int pos = atomicAdd(&cnt[lane], 1);
      tok[lane * T_TOK + pos] = t;
      wt [lane * T_TOK + pos] = mine;
    }
  }
}

// ------- A: fp32 -> scaled fp16 hi/lo split (x*64 = hi + lo), row-major -----
__global__ __launch_bounds__(256) void split_kernel(
    const float* __restrict__ src, f16* __restrict__ hi, f16* __restrict__ lo, int n4)
{
  int i0 = blockIdx.x * 256 + threadIdx.x;
  int stride = gridDim.x * 256;
  for (int i = i0; i < n4; i += stride) {
    fv4 v = ((const fv4*)src)[i];
    f16x4 h4, l4;
#pragma unroll
    for (int j = 0; j < 4; ++j) {
      float x = v[j] * 64.f;       // pre-scale keeps lo parts out of fp16 denormal range
      f16 hh = (f16)x;
      h4[j] = hh;
      l4[j] = (f16)(x - (float)hh);
    }
    ((f16x4*)hi)[i] = h4;
    ((f16x4*)lo)[i] = l4;
  }
}

// ------- W: split + transpose to K-major-16B layout [E][K/8][2048][8] -------
__global__ __launch_bounds__(256) void wsplit_kernel(
    const float* __restrict__ src, f16* __restrict__ hi, f16* __restrict__ lo)
{
  const int eidx = blockIdx.z;
  const int r0   = blockIdx.y * 32;
  const int k0   = blockIdx.x * 64;
  __shared__ f16 th[32 * 9 * 8];   // [32 rows][9 chunk-slots (pad)][8 f16]
  __shared__ f16 tl[32 * 9 * 8];
  const int rr = threadIdx.x >> 3, c8 = threadIdx.x & 7;
  const float* s = src + ((size_t)eidx * DIM + r0 + rr) * DIM + k0 + c8 * 8;
  fv4 v0 = *(const fv4*)s;
  fv4 v1 = *(const fv4*)(s + 4);
  f16x8 hv, lv;
#pragma unroll
  for (int j = 0; j < 4; ++j) {
    float x = v0[j] * 64.f; f16 hh = (f16)x; hv[j] = hh; lv[j] = (f16)(x - (float)hh);
    float y = v1[j] * 64.f; f16 h2 = (f16)y; hv[4 + j] = h2; lv[4 + j] = (f16)(y - (float)h2);
  }
  *(f16x8*)&th[(rr * 9 + c8) * 8] = hv;
  *(f16x8*)&tl[(rr * 9 + c8) * 8] = lv;
  __syncthreads();
  const int c8w = threadIdx.x >> 5, rw = threadIdx.x & 31;
  f16x8 oh = *(const f16x8*)&th[(rw * 9 + c8w) * 8];
  f16x8 ol = *(const f16x8*)&tl[(rw * 9 + c8w) * 8];
  size_t o = (((size_t)eidx * (DIM / 8) + (k0 / 8 + c8w)) * DIM + r0 + rw) * 8;
  *(f16x8*)&hi[o] = oh;
  *(f16x8*)&lo[o] = ol;
}

// --- gathered grouped GEMM, 128x256, A direct-to-reg, W-only LDS dbuf -------
// A-frags (16B/lane gathers, L1/L2-hot) load straight global->VGPR: removes
// A LDS writes+reads (48->96 KB/blk-kt total LDS vs 144) AND the A-buffer
// barrier -> ONE barrier per kt. W stays global_load_lds double-buffered
// (64 KB LDS, 2 blocks/CU). Counted vmcnt(8) waits A while W-stage flies.
// Per kt/wave: 8 global A loads + 16 ds_read -> 96 MFMA (A1W1, A2W1, A1W2).
// Grid: XCD = n-group -> each XCD reads each expert's A slice exactly once.
__global__ __launch_bounds__(256, 2) void moe_gemm(
    const f16* __restrict__ A1, const f16* __restrict__ A2,
    const f16* __restrict__ W1t, const f16* __restrict__ W2t,
    const int* __restrict__ tok, const float* __restrict__ wt,
    const int* __restrict__ cnt, float* __restrict__ out)
{
  // b = 512p + 8q + r -> group w = 8p + r (w = e*8 + nt, XCD = nt), my = q
  const int b  = blockIdx.x;
  const int w  = (b >> 9) * 8 + (b & 7);   // 0..127
  const int my = (b >> 3) & 63;            // 0..63
  const int e  = w >> 3;
  const int ce = cnt[e];
  const int m0 = my * BM;
  if (m0 >= ce) return;
  const int n0 = (w & 7) * BN;

  __shared__ f16 lsW1[2][BN * BK];     // [4 kc][256 row][8], 2 x 16 KB dbuf
  __shared__ f16 lsW2[2][BN * BK];

  const int tid = threadIdx.x;   // 0..255

  // W staging K-major: slot s = tid + 256j: kc = j, row = tid.
  const size_t wbase = (size_t)e * (DIM / 8) * DIM * 8 + ((size_t)n0 + tid) * 8;

  auto stageW = [&](int kt, int bb) {
    const int kc0 = kt * 4;
#pragma unroll
    for (int j = 0; j < 4; ++j) {
      __builtin_amdgcn_global_load_lds(
          (const __attribute__((address_space(1))) void*)(W1t + wbase + (size_t)(kc0 + j) * DIM * 8),
          (__attribute__((address_space(3))) void*)(&lsW1[bb][(tid + 256 * j) * 8]), 16, 0, 0);
      __builtin_amdgcn_global_load_lds(
          (const __attribute__((address_space(1))) void*)(W2t + wbase + (size_t)(kc0 + j) * DIM * 8),
          (__attribute__((address_space(3))) void*)(&lsW2[bb][(tid + 256 * j) * 8]), 16, 0, 0);
    }
  };

  const int lane = tid & 63;
  const int wid  = tid >> 6;
  const int wm   = wid & 1;           // M half (64 rows)
  const int wn   = wid >> 1;          // N half (128 cols)
  const int lr   = lane & 15;
  const int lk   = lane >> 4;         // 0..3 -> k-chunk

  // A byte-voffsets: frag mi -> row wm*64+mi*16+lr, k-chunk lk (16 B)
  uint32_t voff[4];
#pragma unroll
  for (int mi = 0; mi < 4; ++mi) {
    int row = wm * 64 + mi * 16 + lr;
    int pos = min(m0 + row, ce - 1);
    voff[mi] = (uint32_t)tok[e * T_TOK + pos] * (DIM * 2) + lk * 16;
  }
  const char* A1b = (const char*)A1;
  const char* A2b = (const char*)A2;

  f32x4 acc[4][8];
#pragma unroll
  for (int i = 0; i < 4; ++i)
#pragma unroll
    for (int j = 0; j < 8; ++j)
      acc[i][j] = (f32x4){0.f, 0.f, 0.f, 0.f};

  stageW(0, 0);
  asm volatile("s_waitcnt vmcnt(0)" ::: "memory");
  __builtin_amdgcn_s_barrier();
  __builtin_amdgcn_sched_barrier(0);

  int cur = 0;
  for (int kt = 0; kt < NT; ++kt) {
    const bool pf = (kt + 1 < NT);
    const int kb = kt * 64;            // byte offset within A row
    f16x8 a1F[4], a2F[4], w1F[8], w2F[8];

    // ---- issue A global loads (8 vmem), then next-tile W stage (8 vmem)
#pragma unroll
    for (int mi = 0; mi < 4; ++mi)
      a1F[mi] = *(const f16x8*)(A1b + voff[mi] + kb);
#pragma unroll
    for (int mi = 0; mi < 4; ++mi)
      a2F[mi] = *(const f16x8*)(A2b + voff[mi] + kb);
    if (pf) stageW(kt + 1, cur ^ 1);

    // ---- W fragment reads from current buffer (conflict-free sequential)
#pragma unroll
    for (int ni = 0; ni < 8; ++ni) {
      int off = (lk * 256 + wn * 128 + ni * 16 + lr) * 8;
      w1F[ni] = *(const f16x8*)&lsW1[cur][off];
      w2F[ni] = *(const f16x8*)&lsW2[cur][off];
    }
    asm volatile("s_waitcnt lgkmcnt(0)" ::: "memory");   // W frags in regs
    if (pf) asm volatile("s_waitcnt vmcnt(8)" ::: "memory");  // A in, W-stage flying
    else    asm volatile("s_waitcnt vmcnt(0)" ::: "memory");
    __builtin_amdgcn_sched_barrier(0);

    // ---- 3 MFMA clusters, all operands in registers
    __builtin_amdgcn_s_setprio(1);
#pragma unroll
    for (int mi = 0; mi < 4; ++mi)
#pragma unroll
      for (int ni = 0; ni < 8; ++ni)
        acc[mi][ni] = __builtin_amdgcn_mfma_f32_16x16x32_f16(a1F[mi], w1F[ni], acc[mi][ni], 0, 0, 0);
#pragma unroll
    for (int mi = 0; mi < 4; ++mi)
#pragma unroll
      for (int ni = 0; ni < 8; ++ni)
        acc[mi][ni] = __builtin_amdgcn_mfma_f32_16x16x32_f16(a2F[mi], w1F[ni], acc[mi][ni], 0, 0, 0);
#pragma unroll
    for (int mi = 0; mi < 4; ++mi)
#pragma unroll
      for (int ni = 0; ni < 8; ++ni)
        acc[mi][ni] = __builtin_amdgcn_mfma_f32_16x16x32_f16(a1F[mi], w2F[ni], acc[mi][ni], 0, 0, 0);
    __builtin_amdgcn_s_setprio(0);

    if (pf) {
      asm volatile("s_waitcnt vmcnt(0)" ::: "memory");   // W stage for kt+1 landed
      __builtin_amdgcn_s_barrier();                      // all waves done + staged
      __builtin_amdgcn_sched_barrier(0);
    }
    cur ^= 1;
  }

  // epilogue: out[tok, n] += w * acc / 4096  (descale 64*64)
  const int ebase = e * T_TOK;
#pragma unroll
  for (int mi = 0; mi < 4; ++mi) {
#pragma unroll
    for (int q = 0; q < 4; ++q) {
      int pos = m0 + wm * 64 + mi * 16 + lk * 4 + q;
      if (pos < ce) {
        int tt = tok[ebase + pos];
        float sc = wt[ebase + pos] * (1.0f / 4096.0f);
        float* orow = out + (size_t)tt * DIM + n0 + wn * 128;
#pragma unroll
        for (int ni = 0; ni < 8; ++ni)
          atomicAdd(&orow[ni * 16 + lr], sc * acc[mi][ni][q]);
      }
    }
  }
}

// ------------------------------- launcher -----------------------------------
extern "C" void kernel_launch(void* const* d_in, const int* in_sizes, int n_in,
                              void* d_out, int out_size, void* d_ws, size_t ws_size,
                              hipStream_t stream) {
  const float* x  = (const float*)d_in[0];
  const float* gw = (const float*)d_in[1];
  const float* ew = (const float*)d_in[2];
  float* out = (float*)d_out;

  char* ws = (char*)d_ws;
  float* hA  = (float*)ws;                        // 64 MB fp32 h ping buffer
  f16*   A1  = (f16*)(ws + 67108864ull);          // 32 MB
  f16*   A2  = (f16*)(ws + 100663296ull);         // 32 MB
  f16*   W1t = (f16*)(ws + 134217728ull);         // 128 MB (K-major, this layer)
  f16*   W2t = (f16*)(ws + 268435456ull);         // 128 MB
  int*   tok = (int*)(ws + 402653184ull);         // 512 KB
  float* wt  = (float*)(ws + 403177472ull);       // 512 KB
  int*   cnt = (int*)(ws + 403701760ull);         // 64 B

  const float* hin = x;
  float* houts[4] = {hA, out, hA, out};           // ping-pong; final layer -> d_out
  for (int l = 0; l < NLAY; ++l) {
    float* hout = houts[l];
    hipMemsetAsync(cnt, 0, 64, stream);
    route_kernel<<<T_TOK / 4, 256, 0, stream>>>(hin, gw + (size_t)l * NEXP * DIM, cnt, tok, wt);
    split_kernel<<<4096, 256, 0, stream>>>(hin, A1, A2, T_TOK * DIM / 4);
    {
      dim3 gt(DIM / 64, DIM / 32, NEXP);
      wsplit_kernel<<<gt, 256, 0, stream>>>(ew + (size_t)l * NEXP * DIM * DIM, W1t, W2t);
    }
    hipMemsetAsync(hout, 0, (size_t)T_TOK * DIM * 4, stream);
    moe_gemm<<<16 * 64 * 8, 256, 0, stream>>>(A1, A2, W1t, W2t, tok, wt, cnt, hout);
    hin = hout;
  }
}